// Round 4
// baseline (541.465 us; speedup 1.0000x reference)
//
#include <hip/hip_runtime.h>
#include <math.h>

// Problem constants (B, CIN, CGD, CE, G, H, W) = (4, 256, 256, 64, 4, 80, 80)
#define NB    4
#define CINC  256
#define NG    4
#define NPIX  6400          // H*W
#define NROWS 132           // 64 embed + 64 guide_embed + 4 conf
#define CHG   65            // tree-filter channels per group (64 + norm)
#define CHP   80            // padded per-group stride in node-major agg
#define NODEF (NG*CHP)      // 320 floats per node
#define TEPS  1e-8f
#define TP    128           // gemm position tile
#define KC    32            // gemm K chunk
#define GT    256           // gemm threads
#define SCH   5             // sweep channels per block (13 chunks * 5 = 65)
#define SPITCH 6401         // LDS pitch (%32==1 -> writeback 2-way free)
#define SWT   320           // sweep threads: 5 waves, wave w owns channel w
#define PT    640           // prep threads (6400/640 = 10)
#define LSC   512           // level-start LDS cache entries

typedef unsigned short u16;
typedef unsigned int   u32;

// ---------------------------------------------------------------------------
// Preprocessing: per batch — levels via pointer doubling, level starts,
// u16 parent copy, inverse order. 640 threads = 10 items/thread.
// ---------------------------------------------------------------------------
__global__ __launch_bounds__(PT) void prep_kernel(
    const int* __restrict__ order, const int* __restrict__ parent,
    u16* __restrict__ par16, int* __restrict__ ls,
    int* __restrict__ nl, int* __restrict__ inv)
{
  const int b = blockIdx.x;
  const int tid = threadIdx.x;
  const int* par = parent + b*NPIX;
  const int* ord = order + b*NPIX;
  __shared__ int lvl[NPIX];   // 25.6 KB
  __shared__ int anc[NPIX];   // 25.6 KB
  __shared__ int smax;

  #pragma unroll
  for (int it = 0; it < NPIX/PT; ++it) {
    int k = tid + it*PT;
    int p = par[k];
    lvl[k] = (k == 0) ? 0 : 1;
    anc[k] = p;
    inv[b*NPIX + ord[k]] = k;
    par16[b*NPIX + k] = (u16)p;
  }
  __syncthreads();

  // depth via pointer doubling: 13 rounds (2^13 = 8192 > 6400)
  for (int r = 0; r < 13; ++r) {
    int nlv[NPIX/PT], nan_[NPIX/PT];
    #pragma unroll
    for (int it = 0; it < NPIX/PT; ++it) {
      int k = tid + it*PT;
      int a = anc[k];
      nlv[it]  = lvl[k] + lvl[a];
      nan_[it] = anc[a];
    }
    __syncthreads();
    #pragma unroll
    for (int it = 0; it < NPIX/PT; ++it) {
      int k = tid + it*PT;
      lvl[k] = nlv[it];
      anc[k] = nan_[it];
    }
    __syncthreads();
  }

  if (tid == 0) smax = 0;
  __syncthreads();
  int m = 0;
  #pragma unroll
  for (int it = 0; it < NPIX/PT; ++it) m = max(m, lvl[tid + it*PT]);
  atomicMax(&smax, m);
  __syncthreads();
  if (tid == 0) {
    nl[b] = smax + 1;
    ls[b*(NPIX+2) + smax + 1] = NPIX;
  }
  #pragma unroll
  for (int it = 0; it < NPIX/PT; ++it) {
    int k = tid + it*PT;
    // levels are contiguous position ranges (BFS order)
    if (k == 0 || lvl[k] != lvl[k-1]) ls[b*(NPIX+2) + lvl[k]] = k;
  }
}

// ---------------------------------------------------------------------------
// GEMM: emb_all[b][n][r], r in [0,64)=W_embed@f, [64,128)=W_guide@g,
// [128,132)=sigmoid(W_conf@f). Node-major output for later gathers.
// ---------------------------------------------------------------------------
__global__ __launch_bounds__(GT) void gemm_kernel(
    const float* __restrict__ f, const float* __restrict__ g,
    const float* __restrict__ We, const float* __restrict__ Wc,
    const float* __restrict__ Wg, float* __restrict__ emb)
{
  const int b  = blockIdx.y;
  const int t0 = blockIdx.x * TP;
  const int tid = threadIdx.x;
  const int i = tid >> 4;   // 0..15 rowgroup (rows 8i..8i+7)
  const int j = tid & 15;   // 0..15 posgroup

  __shared__ float fT[KC][TP];      // 16 KB
  __shared__ float gT[KC][TP];      // 16 KB
  __shared__ float wTt[KC][136];    // 17.4 KB (transposed, padded pitch)

  float acc[8][8];
  #pragma unroll
  for (int r = 0; r < 8; ++r)
    #pragma unroll
    for (int p = 0; p < 8; ++p) acc[r][p] = 0.f;
  float accc[8];
  #pragma unroll
  for (int p = 0; p < 8; ++p) accc[p] = 0.f;

  const float* fb = f + (size_t)b*CINC*NPIX;
  const float* gb = g + (size_t)b*CINC*NPIX;
  const float (*xT)[TP] = (i < 8) ? fT : gT;   // rows 0..63 use f, 64..127 use g

  for (int kc = 0; kc < CINC; kc += KC) {
    { // stage x tiles: 32x128 each; 16 contiguous floats per thread
      int kk = tid >> 3;
      int p  = (tid & 7) * 16;
      const float4* srcf = reinterpret_cast<const float4*>(fb + (size_t)(kc+kk)*NPIX + t0 + p);
      const float4* srcg = reinterpret_cast<const float4*>(gb + (size_t)(kc+kk)*NPIX + t0 + p);
      float4* df = reinterpret_cast<float4*>(&fT[kk][p]);
      float4* dg = reinterpret_cast<float4*>(&gT[kk][p]);
      #pragma unroll
      for (int q = 0; q < 4; ++q) { df[q] = srcf[q]; dg[q] = srcg[q]; }
    }
    // stage weights transposed: wTt[kb][r]
    for (int s = tid; s < 528; s += GT) {
      int r = s >> 2, kb0 = (s & 3) * 8;
      const float* wsrc;
      if (r < 64)       wsrc = We + r*CINC + kc + kb0;
      else if (r < 128) wsrc = Wg + (r-64)*CINC + kc + kb0;
      else              wsrc = Wc + (r-128)*CINC + kc + kb0;
      const float4* wv = reinterpret_cast<const float4*>(wsrc);
      float4 v0 = wv[0], v1 = wv[1];
      wTt[kb0+0][r]=v0.x; wTt[kb0+1][r]=v0.y; wTt[kb0+2][r]=v0.z; wTt[kb0+3][r]=v0.w;
      wTt[kb0+4][r]=v1.x; wTt[kb0+5][r]=v1.y; wTt[kb0+6][r]=v1.z; wTt[kb0+7][r]=v1.w;
    }
    __syncthreads();

    for (int kk = 0; kk < KC; ++kk) {
      float4 x0 = *reinterpret_cast<const float4*>(&xT[kk][4*j]);
      float4 x1 = *reinterpret_cast<const float4*>(&xT[kk][64 + 4*j]);
      float4 w0 = *reinterpret_cast<const float4*>(&wTt[kk][8*i]);
      float4 w1 = *reinterpret_cast<const float4*>(&wTt[kk][8*i + 4]);
#define FMA8(r, wv) \
      acc[r][0] += (wv)*x0.x; acc[r][1] += (wv)*x0.y; acc[r][2] += (wv)*x0.z; acc[r][3] += (wv)*x0.w; \
      acc[r][4] += (wv)*x1.x; acc[r][5] += (wv)*x1.y; acc[r][6] += (wv)*x1.z; acc[r][7] += (wv)*x1.w;
      FMA8(0, w0.x) FMA8(1, w0.y) FMA8(2, w0.z) FMA8(3, w0.w)
      FMA8(4, w1.x) FMA8(5, w1.y) FMA8(6, w1.z) FMA8(7, w1.w)
#undef FMA8
      if (i < 4) {
        float wcf = wTt[kk][128 + i];
        accc[0] += wcf*x0.x; accc[1] += wcf*x0.y; accc[2] += wcf*x0.z; accc[3] += wcf*x0.w;
        accc[4] += wcf*x1.x; accc[5] += wcf*x1.y; accc[6] += wcf*x1.z; accc[7] += wcf*x1.w;
      }
    }
    __syncthreads();
  }

  float* eb = emb + (size_t)b*NPIX*NROWS;
  #pragma unroll
  for (int p = 0; p < 8; ++p) {
    int n = t0 + ((p >> 2) * 64) + 4*j + (p & 3);
    float4 v0 = make_float4(acc[0][p], acc[1][p], acc[2][p], acc[3][p]);
    float4 v1 = make_float4(acc[4][p], acc[5][p], acc[6][p], acc[7][p]);
    float* base = eb + (size_t)n*NROWS + 8*i;
    *reinterpret_cast<float4*>(base)     = v0;
    *reinterpret_cast<float4*>(base + 4) = v1;
    if (i < 4) eb[(size_t)n*NROWS + 128 + i] = 1.f / (1.f + expf(-accc[p]));
  }
}

// ---------------------------------------------------------------------------
// Edge weights, quantized u16, transposed: wq[b][g][k] = round(65535*w)
// ---------------------------------------------------------------------------
__global__ __launch_bounds__(256) void wdist_kernel(
    const float* __restrict__ emb, const int* __restrict__ order,
    const int* __restrict__ parent, const float* __restrict__ beta,
    u16* __restrict__ wq)
{
  int idx = blockIdx.x*256 + threadIdx.x;   // b*NPIX + k
  int b = idx / NPIX;
  int k = idx - b*NPIX;
  int n  = order[idx];
  int kp = parent[idx];
  int np = order[b*NPIX + kp];
  const float4* e0 = reinterpret_cast<const float4*>(emb + ((size_t)b*NPIX + n )*NROWS);
  const float4* e1 = reinterpret_cast<const float4*>(emb + ((size_t)b*NPIX + np)*NROWS);
  float d[NG] = {0.f, 0.f, 0.f, 0.f};
  #pragma unroll
  for (int q = 0; q < 32; ++q) {            // channels 0..127 (embed then guide_embed)
    float4 a = e0[q], c = e1[q];
    int gg = (q & 15) >> 2;                 // group = (channel%64)/16
    float t0 = a.x-c.x, t1 = a.y-c.y, t2 = a.z-c.z, t3 = a.w-c.w;
    d[gg] += t0*t0 + t1*t1 + t2*t2 + t3*t3;
  }
  #pragma unroll
  for (int gg = 0; gg < NG; ++gg) {
    float bg = beta[gg];
    float w = expf(-(d[gg] + bg*bg));
    wq[((size_t)(b*NG+gg))*NPIX + k] = (u16)(w*65535.f + 0.5f);
  }
}

// ---------------------------------------------------------------------------
// Build composite-hop tables for the 2-level sweep:
//   G1[b][k]  = (gp << 16) | p            (parent, grandparent)
//   G2[bg][k] = (w[p] << 16) | w[k]       (own & parent edge weights, u16)
// ---------------------------------------------------------------------------
__global__ __launch_bounds__(256) void gbuild_kernel(
    const u16* __restrict__ par16, const u16* __restrict__ wq,
    u32* __restrict__ G1, u32* __restrict__ G2)
{
  int idx = blockIdx.x*256 + threadIdx.x;   // b*NPIX + k
  int b = idx / NPIX, k = idx - b*NPIX;
  int p  = par16[idx];
  int gp = par16[b*NPIX + p];
  G1[idx] = ((u32)gp << 16) | (u32)p;
  #pragma unroll
  for (int g = 0; g < NG; ++g) {
    size_t bg = (size_t)(b*NG + g)*NPIX;
    u32 wk = wq[bg + k];
    u32 wp = wq[bg + p];
    G2[bg + k] = (wp << 16) | wk;
  }
}

// ---------------------------------------------------------------------------
// x in spatial space: xsp[b][n][g*65+c] = f[g*64+c]*conf[g]; c=64 -> conf[g]
// ---------------------------------------------------------------------------
__global__ __launch_bounds__(256) void xbuild_kernel(
    const float* __restrict__ f, const float* __restrict__ emb,
    float* __restrict__ xsp)
{
  int idx = blockIdx.x*256 + threadIdx.x;   // b*NPIX + n
  int b = idx / NPIX, n = idx - b*NPIX;
  const float* eb = emb + (size_t)idx*NROWS;
  float cf[NG];
  #pragma unroll
  for (int gg = 0; gg < NG; ++gg) cf[gg] = eb[128 + gg];
  const float* fb = f + (size_t)b*CINC*NPIX + n;
  float* xb = xsp + (size_t)idx*260;
  #pragma unroll 4
  for (int ch = 0; ch < CINC; ++ch) {
    int gg = ch >> 6, cc = ch & 63;
    xb[gg*CHG + cc] = fb[(size_t)ch*NPIX] * cf[gg];
  }
  #pragma unroll
  for (int gg = 0; gg < NG; ++gg) xb[gg*CHG + 64] = cf[gg];
}

// ---------------------------------------------------------------------------
// Transpose-gather to channel-major ordered layout: aggT[b][g][c][k]
// Block = (b, g, 64-node tile). LDS-tiled so both sides are coalesced.
// ---------------------------------------------------------------------------
__global__ __launch_bounds__(256) void gatherT_kernel(
    const float* __restrict__ xsp, const int* __restrict__ order,
    float* __restrict__ aggT)
{
  int bid = blockIdx.x;                 // b*400 + g*100 + tile
  int b = bid / 400, r = bid - b*400;
  int g = r / 100, k0 = (r - g*100) * 64;
  const int tid = threadIdx.x;

  __shared__ float tile[64][66];
  __shared__ int s_ord[64];
  if (tid < 64) s_ord[tid] = order[b*NPIX + k0 + tid];
  __syncthreads();

  for (int idx = tid; idx < 64*65; idx += 256) {
    int kk = idx / 65, c = idx - kk*65;
    tile[kk][c] = xsp[((size_t)b*NPIX + s_ord[kk])*260 + g*65 + c];
  }
  __syncthreads();
  float* dst = aggT + ((size_t)(b*NG+g)*CHG)*NPIX;
  for (int idx = tid; idx < 65*64; idx += 256) {
    int c = idx / 64, kk = idx - c*64;
    dst[(size_t)c*NPIX + k0 + kk] = tile[kk][c];
  }
}

// ---------------------------------------------------------------------------
// Tree filter, LDS-resident. Block = (b, g, 5-channel chunk), 320 threads =
// 5 waves; wave w owns channel w exclusively (no block barriers in sweeps).
// R4: TWO LEVELS PER SERIAL STEP via affine composition:
//   UP  : grandchildren scatter w*wp*V directly into grandparents; middle
//         level scatters with PRE-step values (read before any adds land).
//   DOWN: deep nodes computed from grandparent's final value in registers.
// Per-node (p,gp,w,wp) come from G1/G2 global tables, register-prefetched
// one step ahead (contiguous per level, L2-resident) => no dependent LDS
// address lookups in the chain. LDS holds only s_agg + level starts.
// ---------------------------------------------------------------------------
__global__ __launch_bounds__(SWT, 1) void sweep_kernel(
    const float* __restrict__ aggT, const int* __restrict__ ls,
    const int* __restrict__ nl, const u32* __restrict__ G1,
    const u32* __restrict__ G2, float* __restrict__ agg)
{
  extern __shared__ char smem[];
  float* s_agg = (float*)smem;                 // 5*6401*4 = 128,020 B (pad 12)
  int*   s_ls  = (int*)(smem + 128032);        // 2,048 B

  const int bid = blockIdx.x;
  const int b = bid / (NG*13);
  const int r = bid - b*(NG*13);
  const int g = r / 13;
  const int ch0 = (r - g*13) * SCH;
  const int tid = threadIdx.x;
  const int ld = tid & 63;
  const int cw = tid >> 6;          // wave id == owned channel (0..4)
  const int bg = b*NG + g;

  // ---- stage: each wave loads its own channel plane (coalesced float4) ----
  {
    const float4* src = reinterpret_cast<const float4*>(aggT + ((size_t)bg*CHG + ch0 + cw)*NPIX);
    float* dst = s_agg + cw*SPITCH;
    for (int i = ld; i < NPIX/4; i += 64) {
      float4 v = src[i];
      int k = i*4;
      dst[k] = v.x; dst[k+1] = v.y; dst[k+2] = v.z; dst[k+3] = v.w;
    }
  }
  const int* lsb = ls + b*(NPIX+2);
  const int L = nl[b];
  for (int i = tid; i <= L && i < LSC; i += SWT) s_ls[i] = lsb[i];
  __syncthreads();

  const float qs = 1.0f/65535.0f;
  float* sa = s_agg + cw*SPITCH;
  const u32* g1b = G1 + b*NPIX;
  const u32* g2b = G2 + (size_t)bg*NPIX;
  auto LS = [&](int x) -> int { x = min(x, L); return (x < LSC) ? s_ls[x] : lsb[x]; };

  // ================= UP: targets (t_hi, t_hi-1) per step =================
  {
    int t_hi = L-2;
    int sD = LS(t_hi+1), eD = LS(t_hi+2);          // S_deep = level t_hi+1
    int sM = 0, eM = 0;                            // S_mid  = level t_hi
    if (t_hi >= 1) { sM = LS(t_hi); eM = sD; }
    u32 g1D=0, g2D=0, g1M=0, g2M=0;
    if (sD + ld < eD) { g1D = g1b[sD+ld]; g2D = g2b[sD+ld]; }
    if (sM + ld < eM) { g1M = g1b[sM+ld]; g2M = g2b[sM+ld]; }

    while (t_hi >= 0) {
      int nt = t_hi - 2;
      // next ranges (LDS broadcast reads, drained by the lgkm below)
      int nsD=0, neD=0, nsM=0, neM=0;
      if (nt >= 0) {
        nsD = LS(nt+1); neD = LS(nt+2);
        if (nt >= 1) { nsM = LS(nt); neM = nsD; }
      }
      // phase1: value reads (mid values are PRE-step; deep values final)
      int kD = sD + ld, kM = sM + ld;
      bool aD = kD < eD, aM = kM < eM;
      float vD = aD ? sa[kD] : 0.f;
      float vM = aM ? sa[kM] : 0.f;
      asm volatile("s_waitcnt vmcnt(0)" ::: "memory");   // current G ready
      u32 c1D=g1D, c2D=g2D, c1M=g1M, c2M=g2M;
      asm volatile("s_waitcnt lgkmcnt(0)" ::: "memory"); // values + ranges ready
      // prefetch next step's G
      if (nt >= 0) {
        g1D=0; g2D=0; g1M=0; g2M=0;
        if (nsD + ld < neD) { g1D = g1b[nsD+ld]; g2D = g2b[nsD+ld]; }
        if (nsM + ld < neM) { g1M = g1b[nsM+ld]; g2M = g2b[nsM+ld]; }
      }
      // phase2a: mid scatters (into t_hi-1) — all mid READS precede deep adds
      if (aM) {
        float wk = (float)(c2M & 0xffffu) * qs;
        atomicAdd(&sa[c1M & 0xffffu], wk*vM);
      }
      for (int k = sM + 64 + ld; k < eM; k += 64) {   // rare wide level
        u32 a1 = g1b[k], a2 = g2b[k];
        float v = sa[k];
        float wk = (float)(a2 & 0xffffu) * qs;
        atomicAdd(&sa[a1 & 0xffffu], wk*v);
      }
      asm volatile("" ::: "memory");
      // phase2b: deep scatters (into t_hi via p, and t_hi-1 via gp)
      if (aD) {
        float wk = (float)(c2D & 0xffffu) * qs;
        atomicAdd(&sa[c1D & 0xffffu], wk*vD);
        if (t_hi >= 1) {
          float wp = (float)(c2D >> 16) * qs;
          atomicAdd(&sa[c1D >> 16], wk*wp*vD);
        }
      }
      for (int k = sD + 64 + ld; k < eD; k += 64) {   // rare wide level
        u32 a1 = g1b[k], a2 = g2b[k];
        float v = sa[k];
        float wk = (float)(a2 & 0xffffu) * qs;
        atomicAdd(&sa[a1 & 0xffffu], wk*v);
        if (t_hi >= 1) {
          float wp = (float)(a2 >> 16) * qs;
          atomicAdd(&sa[a1 >> 16], wk*wp*v);
        }
      }
      asm volatile("s_waitcnt lgkmcnt(0)" ::: "memory"); // adds visible
      sD=nsD; eD=neD; sM=nsM; eM=neM; t_hi = nt;
    }
  }

  // ================ DOWN: targets (t_lo, t_lo+1) per step ================
  {
    int t_lo = 1;
    int sS = LS(1), eS = LS(2);                     // shallow = level t_lo
    int sDn=0, eDn=0;                               // deep    = level t_lo+1
    if (2 <= L-1) { sDn = eS; eDn = LS(3); }
    u32 g1S=0, g2S=0, g1D=0, g2D=0;
    if (sS + ld < eS)  { g1S = g1b[sS+ld];  g2S = g2b[sS+ld]; }
    if (sDn + ld < eDn){ g1D = g1b[sDn+ld]; g2D = g2b[sDn+ld]; }

    while (t_lo <= L-1) {
      int nt = t_lo + 2;
      asm volatile("s_waitcnt vmcnt(0)" ::: "memory");   // need G for addresses
      int pS  = g1S & 0xffffu;  float wS  = (float)(g2S & 0xffffu)*qs;
      int pD  = g1D & 0xffffu;  int gpD = g1D >> 16;
      float wD  = (float)(g2D & 0xffffu)*qs;
      float wPD = (float)(g2D >> 16)*qs;
      // next ranges
      int nsS=0, neS=0, nsD=0, neD=0;
      if (nt <= L-1) {
        nsS = LS(nt); neS = LS(nt+1);
        if (nt+1 <= L-1) { nsD = neS; neD = LS(nt+2); }
      }
      // phase1: reads (a-values are PRE-step; out[parent/gp] final)
      int kS = sS + ld, kD = sDn + ld;
      bool aS = kS < eS, aD2 = kD < eDn;
      float aSv=0.f, oP=0.f, aDv=0.f, aPv=0.f, oGP=0.f;
      if (aS)  { aSv = sa[kS]; oP  = sa[pS]; }
      if (aD2) { aDv = sa[kD]; aPv = sa[pD]; oGP = sa[gpD]; }
      asm volatile("s_waitcnt lgkmcnt(0)" ::: "memory");
      // prefetch next step's G
      if (nt <= L-1) {
        g1S=0; g2S=0; g1D=0; g2D=0;
        if (nsS + ld < neS) { g1S = g1b[nsS+ld]; g2S = g2b[nsS+ld]; }
        if (nsD + ld < neD) { g1D = g1b[nsD+ld]; g2D = g2b[nsD+ld]; }
      }
      // phase2a: deep writes (reads of a[p] at t_lo already done / done here)
      if (aD2) {
        float t = fmaf(wPD, oGP - wPD*aPv, aPv);     // == out[p] (final formula)
        sa[kD] = fmaf(wD, t - wD*aDv, aDv);
      }
      for (int k = sDn + 64 + ld; k < eDn; k += 64) { // rare wide level
        u32 a1 = g1b[k], a2 = g2b[k];
        int p = a1 & 0xffffu, gp = a1 >> 16;
        float wj = (float)(a2 & 0xffffu)*qs, wp = (float)(a2 >> 16)*qs;
        float aj = sa[k], ap = sa[p], og = sa[gp];
        float t2 = fmaf(wp, og - wp*ap, ap);
        sa[k] = fmaf(wj, t2 - wj*aj, aj);
      }
      asm volatile("" ::: "memory");
      // phase2b: shallow writes (after ALL deep reads of level t_lo)
      if (aS) sa[kS] = fmaf(wS, oP - wS*aSv, aSv);
      for (int k = sS + 64 + ld; k < eS; k += 64) {   // rare wide level
        u32 a1 = g1b[k], a2 = g2b[k];
        int p = a1 & 0xffffu;
        float wk = (float)(a2 & 0xffffu)*qs;
        float ak = sa[k], op2 = sa[p];
        sa[k] = fmaf(wk, op2 - wk*ak, ak);
      }
      asm volatile("s_waitcnt lgkmcnt(0)" ::: "memory"); // writes visible
      sS=nsS; eS=neS; sDn=nsD; eDn=neD; t_lo = nt;
    }
  }

  __syncthreads();

  // ---- writeback node-major for epilogue (cooperative) ----
  for (int t = tid; t < NPIX*SCH; t += SWT) {
    int k = t / SCH, c = t - k*SCH;
    agg[((size_t)b*NPIX + k)*NODEF + g*CHP + ch0 + c] = s_agg[c*SPITCH + k];
  }
}

// ---------------------------------------------------------------------------
// Epilogue: gather back to spatial, normalize, residual, store
// ---------------------------------------------------------------------------
__global__ __launch_bounds__(256) void epilogue_kernel(
    const float* __restrict__ agg, const int* __restrict__ inv,
    const float* __restrict__ f, const float* __restrict__ gamma,
    float* __restrict__ out)
{
  int idx = blockIdx.x*256 + threadIdx.x;   // b*NPIX + n
  int b = idx / NPIX, n = idx - b*NPIX;
  int k = inv[idx];
  const float* ab = agg + ((size_t)b*NPIX + k)*NODEF;
  float gam = gamma[0];
  const float* fb = f + (size_t)b*CINC*NPIX + n;
  float* ob = out + (size_t)b*CINC*NPIX + n;
  #pragma unroll
  for (int gg = 0; gg < NG; ++gg) {
    float rn = 1.f / (TEPS + ab[gg*CHP + 64]);
    #pragma unroll 4
    for (int cc = 0; cc < 64; ++cc) {
      int ch = gg*64 + cc;
      float res = ab[gg*CHP + cc] * rn;
      float fv  = fb[(size_t)ch*NPIX];
      ob[(size_t)ch*NPIX] = gam*res + fv;
    }
  }
}

// ---------------------------------------------------------------------------
extern "C" void kernel_launch(void* const* d_in, const int* in_sizes, int n_in,
                              void* d_out, int out_size, void* d_ws, size_t ws_size,
                              hipStream_t stream)
{
  const float* f     = (const float*)d_in[0];
  const float* g     = (const float*)d_in[1];
  const float* We    = (const float*)d_in[2];
  const float* Wc    = (const float*)d_in[3];
  const float* Wg    = (const float*)d_in[4];
  const float* beta  = (const float*)d_in[5];
  const float* gamma = (const float*)d_in[6];
  const int* order   = (const int*)d_in[7];
  const int* parent  = (const int*)d_in[8];
  float* out = (float*)d_out;

  char* ws = (char*)d_ws;
  size_t off = 0;
  auto carve = [&](size_t bytes) -> void* {
    void* p = ws + off;
    off = (off + bytes + 255) & ~(size_t)255;
    return p;
  };
  // agg (node-major, 32.8 MB) aliases [emb + xsp] (40.2 MB), both dead
  // by the time sweep_kernel writes it.
  float* agg = (float*)ws;
  float* emb = (float*)carve((size_t)NB*NPIX*NROWS*4);     // 13.5 MB
  float* xsp = (float*)carve((size_t)NB*NPIX*260*4);       // 26.6 MB
  float* aggT= (float*)carve((size_t)NB*NG*CHG*NPIX*4);    // 26.6 MB
  u16*  wq   = (u16*) carve((size_t)NB*NG*NPIX*2);         // 0.2 MB
  u16*  par16= (u16*) carve((size_t)NB*NPIX*2);
  int*  ls   = (int*) carve((size_t)NB*(NPIX+2)*4);
  int*  nl   = (int*) carve((size_t)NB*4);
  int*  inv  = (int*) carve((size_t)NB*NPIX*4);
  u32*  G1   = (u32*) carve((size_t)NB*NPIX*4);            // 0.1 MB
  u32*  G2   = (u32*) carve((size_t)NB*NG*NPIX*4);         // 0.4 MB

  const int sweep_lds = 128032 + 2048;                     // 130,080 B
  hipFuncSetAttribute((const void*)sweep_kernel,
                      hipFuncAttributeMaxDynamicSharedMemorySize, sweep_lds);

  hipLaunchKernelGGL(prep_kernel,    dim3(NB),           dim3(PT), 0, stream,
                     order, parent, par16, ls, nl, inv);
  hipLaunchKernelGGL(gemm_kernel,    dim3(NPIX/TP, NB),  dim3(GT), 0, stream,
                     f, g, We, Wc, Wg, emb);
  hipLaunchKernelGGL(wdist_kernel,   dim3(NB*NPIX/256),  dim3(256), 0, stream,
                     emb, order, parent, beta, wq);
  hipLaunchKernelGGL(gbuild_kernel,  dim3(NB*NPIX/256),  dim3(256), 0, stream,
                     par16, wq, G1, G2);
  hipLaunchKernelGGL(xbuild_kernel,  dim3(NB*NPIX/256),  dim3(256), 0, stream,
                     f, emb, xsp);
  hipLaunchKernelGGL(gatherT_kernel, dim3(NB*NG*100),    dim3(256), 0, stream,
                     xsp, order, aggT);
  hipLaunchKernelGGL(sweep_kernel,   dim3(NB*NG*13),     dim3(SWT), sweep_lds, stream,
                     aggT, ls, nl, G1, G2, agg);
  hipLaunchKernelGGL(epilogue_kernel,dim3(NB*NPIX/256),  dim3(256), 0, stream,
                     agg, inv, f, gamma, out);
}

// Round 5
// 438.338 us; speedup vs baseline: 1.2353x; 1.2353x over previous
//
#include <hip/hip_runtime.h>
#include <math.h>

// Problem constants (B, CIN, CGD, CE, G, H, W) = (4, 256, 256, 64, 4, 80, 80)
#define NB    4
#define CINC  256
#define NG    4
#define NPIX  6400          // H*W
#define NROWS 132           // 64 embed + 64 guide_embed + 4 conf
#define CHG   65            // tree-filter channels per group (64 + norm)
#define CHP   80            // padded per-group stride in node-major agg
#define NODEF (NG*CHP)      // 320 floats per node
#define TEPS  1e-8f
#define TP    128           // gemm position tile
#define KC    32            // gemm K chunk
#define GT    256           // gemm threads
#define SCH   5             // sweep channels per block (13 chunks * 5 = 65)
#define SPITCH 6413         // LDS pitch: %32==13 -> clean writeback banks
#define SWT   320           // sweep threads: 5 waves, wave w owns channel w
#define PT    640           // prep threads (6400/640 = 10)
#define LSC   512           // level-start LDS cache entries

typedef unsigned short u16;
typedef unsigned int   u32;

// ---------------------------------------------------------------------------
// Preprocessing: per batch — levels via pointer doubling, level starts,
// u16 parent copy, inverse order. 640 threads = 10 items/thread.
// ---------------------------------------------------------------------------
__global__ __launch_bounds__(PT) void prep_kernel(
    const int* __restrict__ order, const int* __restrict__ parent,
    u16* __restrict__ par16, int* __restrict__ ls,
    int* __restrict__ nl, int* __restrict__ inv)
{
  const int b = blockIdx.x;
  const int tid = threadIdx.x;
  const int* par = parent + b*NPIX;
  const int* ord = order + b*NPIX;
  __shared__ int lvl[NPIX];   // 25.6 KB
  __shared__ int anc[NPIX];   // 25.6 KB
  __shared__ int smax;

  #pragma unroll
  for (int it = 0; it < NPIX/PT; ++it) {
    int k = tid + it*PT;
    int p = par[k];
    lvl[k] = (k == 0) ? 0 : 1;
    anc[k] = p;
    inv[b*NPIX + ord[k]] = k;
    par16[b*NPIX + k] = (u16)p;
  }
  __syncthreads();

  // depth via pointer doubling: 13 rounds (2^13 = 8192 > 6400)
  for (int r = 0; r < 13; ++r) {
    int nlv[NPIX/PT], nan_[NPIX/PT];
    #pragma unroll
    for (int it = 0; it < NPIX/PT; ++it) {
      int k = tid + it*PT;
      int a = anc[k];
      nlv[it]  = lvl[k] + lvl[a];
      nan_[it] = anc[a];
    }
    __syncthreads();
    #pragma unroll
    for (int it = 0; it < NPIX/PT; ++it) {
      int k = tid + it*PT;
      lvl[k] = nlv[it];
      anc[k] = nan_[it];
    }
    __syncthreads();
  }

  if (tid == 0) smax = 0;
  __syncthreads();
  int m = 0;
  #pragma unroll
  for (int it = 0; it < NPIX/PT; ++it) m = max(m, lvl[tid + it*PT]);
  atomicMax(&smax, m);
  __syncthreads();
  if (tid == 0) {
    nl[b] = smax + 1;
    ls[b*(NPIX+2) + smax + 1] = NPIX;
  }
  #pragma unroll
  for (int it = 0; it < NPIX/PT; ++it) {
    int k = tid + it*PT;
    // levels are contiguous position ranges (BFS order)
    if (k == 0 || lvl[k] != lvl[k-1]) ls[b*(NPIX+2) + lvl[k]] = k;
  }
}

// ---------------------------------------------------------------------------
// GEMM: emb_all[b][n][r], r in [0,64)=W_embed@f, [64,128)=W_guide@g,
// [128,132)=sigmoid(W_conf@f). Node-major output for later gathers.
// All inner-loop LDS reads are b128 (weights staged transposed).
// ---------------------------------------------------------------------------
__global__ __launch_bounds__(GT) void gemm_kernel(
    const float* __restrict__ f, const float* __restrict__ g,
    const float* __restrict__ We, const float* __restrict__ Wc,
    const float* __restrict__ Wg, float* __restrict__ emb)
{
  const int b  = blockIdx.y;
  const int t0 = blockIdx.x * TP;
  const int tid = threadIdx.x;
  const int i = tid >> 4;   // 0..15 rowgroup (rows 8i..8i+7)
  const int j = tid & 15;   // 0..15 posgroup

  __shared__ float fT[KC][TP];      // 16 KB
  __shared__ float gT[KC][TP];      // 16 KB
  __shared__ float wTt[KC][136];    // 17.4 KB (transposed, padded pitch)

  float acc[8][8];
  #pragma unroll
  for (int r = 0; r < 8; ++r)
    #pragma unroll
    for (int p = 0; p < 8; ++p) acc[r][p] = 0.f;
  float accc[8];
  #pragma unroll
  for (int p = 0; p < 8; ++p) accc[p] = 0.f;

  const float* fb = f + (size_t)b*CINC*NPIX;
  const float* gb = g + (size_t)b*CINC*NPIX;
  const float (*xT)[TP] = (i < 8) ? fT : gT;   // rows 0..63 use f, 64..127 use g

  for (int kc = 0; kc < CINC; kc += KC) {
    { // stage x tiles: 32x128 each; 16 contiguous floats per thread
      int kk = tid >> 3;
      int p  = (tid & 7) * 16;
      const float4* srcf = reinterpret_cast<const float4*>(fb + (size_t)(kc+kk)*NPIX + t0 + p);
      const float4* srcg = reinterpret_cast<const float4*>(gb + (size_t)(kc+kk)*NPIX + t0 + p);
      float4* df = reinterpret_cast<float4*>(&fT[kk][p]);
      float4* dg = reinterpret_cast<float4*>(&gT[kk][p]);
      #pragma unroll
      for (int q = 0; q < 4; ++q) { df[q] = srcf[q]; dg[q] = srcg[q]; }
    }
    // stage weights transposed: wTt[kb][r]
    for (int s = tid; s < 528; s += GT) {
      int r = s >> 2, kb0 = (s & 3) * 8;
      const float* wsrc;
      if (r < 64)       wsrc = We + r*CINC + kc + kb0;
      else if (r < 128) wsrc = Wg + (r-64)*CINC + kc + kb0;
      else              wsrc = Wc + (r-128)*CINC + kc + kb0;
      const float4* wv = reinterpret_cast<const float4*>(wsrc);
      float4 v0 = wv[0], v1 = wv[1];
      wTt[kb0+0][r]=v0.x; wTt[kb0+1][r]=v0.y; wTt[kb0+2][r]=v0.z; wTt[kb0+3][r]=v0.w;
      wTt[kb0+4][r]=v1.x; wTt[kb0+5][r]=v1.y; wTt[kb0+6][r]=v1.z; wTt[kb0+7][r]=v1.w;
    }
    __syncthreads();

    for (int kk = 0; kk < KC; ++kk) {
      float4 x0 = *reinterpret_cast<const float4*>(&xT[kk][4*j]);
      float4 x1 = *reinterpret_cast<const float4*>(&xT[kk][64 + 4*j]);
      float4 w0 = *reinterpret_cast<const float4*>(&wTt[kk][8*i]);
      float4 w1 = *reinterpret_cast<const float4*>(&wTt[kk][8*i + 4]);
#define FMA8(r, wv) \
      acc[r][0] += (wv)*x0.x; acc[r][1] += (wv)*x0.y; acc[r][2] += (wv)*x0.z; acc[r][3] += (wv)*x0.w; \
      acc[r][4] += (wv)*x1.x; acc[r][5] += (wv)*x1.y; acc[r][6] += (wv)*x1.z; acc[r][7] += (wv)*x1.w;
      FMA8(0, w0.x) FMA8(1, w0.y) FMA8(2, w0.z) FMA8(3, w0.w)
      FMA8(4, w1.x) FMA8(5, w1.y) FMA8(6, w1.z) FMA8(7, w1.w)
#undef FMA8
      if (i < 4) {
        float wcf = wTt[kk][128 + i];
        accc[0] += wcf*x0.x; accc[1] += wcf*x0.y; accc[2] += wcf*x0.z; accc[3] += wcf*x0.w;
        accc[4] += wcf*x1.x; accc[5] += wcf*x1.y; accc[6] += wcf*x1.z; accc[7] += wcf*x1.w;
      }
    }
    __syncthreads();
  }

  float* eb = emb + (size_t)b*NPIX*NROWS;
  #pragma unroll
  for (int p = 0; p < 8; ++p) {
    int n = t0 + ((p >> 2) * 64) + 4*j + (p & 3);
    float4 v0 = make_float4(acc[0][p], acc[1][p], acc[2][p], acc[3][p]);
    float4 v1 = make_float4(acc[4][p], acc[5][p], acc[6][p], acc[7][p]);
    float* base = eb + (size_t)n*NROWS + 8*i;
    *reinterpret_cast<float4*>(base)     = v0;
    *reinterpret_cast<float4*>(base + 4) = v1;
    if (i < 4) eb[(size_t)n*NROWS + 128 + i] = 1.f / (1.f + expf(-accc[p]));
  }
}

// ---------------------------------------------------------------------------
// Edge weights, quantized u16, transposed: wq[b][g][k] = round(65535*w)
// ---------------------------------------------------------------------------
__global__ __launch_bounds__(256) void wdist_kernel(
    const float* __restrict__ emb, const int* __restrict__ order,
    const int* __restrict__ parent, const float* __restrict__ beta,
    u16* __restrict__ wq)
{
  int idx = blockIdx.x*256 + threadIdx.x;   // b*NPIX + k
  int b = idx / NPIX;
  int k = idx - b*NPIX;
  int n  = order[idx];
  int kp = parent[idx];
  int np = order[b*NPIX + kp];
  const float4* e0 = reinterpret_cast<const float4*>(emb + ((size_t)b*NPIX + n )*NROWS);
  const float4* e1 = reinterpret_cast<const float4*>(emb + ((size_t)b*NPIX + np)*NROWS);
  float d[NG] = {0.f, 0.f, 0.f, 0.f};
  #pragma unroll
  for (int q = 0; q < 32; ++q) {            // channels 0..127 (embed then guide_embed)
    float4 a = e0[q], c = e1[q];
    int gg = (q & 15) >> 2;                 // group = (channel%64)/16
    float t0 = a.x-c.x, t1 = a.y-c.y, t2 = a.z-c.z, t3 = a.w-c.w;
    d[gg] += t0*t0 + t1*t1 + t2*t2 + t3*t3;
  }
  #pragma unroll
  for (int gg = 0; gg < NG; ++gg) {
    float bg = beta[gg];
    float w = expf(-(d[gg] + bg*bg));
    wq[((size_t)(b*NG+gg))*NPIX + k] = (u16)(w*65535.f + 0.5f);
  }
}

// ---------------------------------------------------------------------------
// x in spatial space: xsp[b][n][g*65+c] = f[g*64+c]*conf[g]; c=64 -> conf[g]
// ---------------------------------------------------------------------------
__global__ __launch_bounds__(256) void xbuild_kernel(
    const float* __restrict__ f, const float* __restrict__ emb,
    float* __restrict__ xsp)
{
  int idx = blockIdx.x*256 + threadIdx.x;   // b*NPIX + n
  int b = idx / NPIX, n = idx - b*NPIX;
  const float* eb = emb + (size_t)idx*NROWS;
  float cf[NG];
  #pragma unroll
  for (int gg = 0; gg < NG; ++gg) cf[gg] = eb[128 + gg];
  const float* fb = f + (size_t)b*CINC*NPIX + n;
  float* xb = xsp + (size_t)idx*260;
  #pragma unroll 4
  for (int ch = 0; ch < CINC; ++ch) {
    int gg = ch >> 6, cc = ch & 63;
    xb[gg*CHG + cc] = fb[(size_t)ch*NPIX] * cf[gg];
  }
  #pragma unroll
  for (int gg = 0; gg < NG; ++gg) xb[gg*CHG + 64] = cf[gg];
}

// ---------------------------------------------------------------------------
// Transpose-gather to channel-major ordered layout: aggT[b][g][c][k]
// Block = (b, g, 64-node tile). LDS-tiled so both sides are coalesced.
// ---------------------------------------------------------------------------
__global__ __launch_bounds__(256) void gatherT_kernel(
    const float* __restrict__ xsp, const int* __restrict__ order,
    float* __restrict__ aggT)
{
  int bid = blockIdx.x;                 // b*400 + g*100 + tile
  int b = bid / 400, r = bid - b*400;
  int g = r / 100, k0 = (r - g*100) * 64;
  const int tid = threadIdx.x;

  __shared__ float tile[64][66];
  __shared__ int s_ord[64];
  if (tid < 64) s_ord[tid] = order[b*NPIX + k0 + tid];
  __syncthreads();

  for (int idx = tid; idx < 64*65; idx += 256) {
    int kk = idx / 65, c = idx - kk*65;
    tile[kk][c] = xsp[((size_t)b*NPIX + s_ord[kk])*260 + g*65 + c];
  }
  __syncthreads();
  float* dst = aggT + ((size_t)(b*NG+g)*CHG)*NPIX;
  for (int idx = tid; idx < 65*64; idx += 256) {
    int c = idx / 64, kk = idx - c*64;
    dst[(size_t)c*NPIX + k0 + kk] = tile[kk][c];
  }
}

// ---------------------------------------------------------------------------
// Tree filter, LDS-resident. Block = (b, g, 5-channel chunk), 320 threads =
// 5 waves; wave w owns channel w exclusively. R5 KEY CHANGE: DS instructions
// from one wave execute IN ORDER through the LDS pipe, so the RAW hazard
// "level t's ds_add/ds_write -> level t+1's ds_read" needs NO hardware
// s_waitcnt between levels. Per-level sync is a COMPILER-ONLY fence
// (asm volatile("" ::: "memory")) pinning program order; the compiler's own
// counted lgkmcnt before each value use covers register deps. This removes
// the add-commit round-trip (~120+ cy) from every one of the ~690 serial
// steps. Level bounds cached in LDS (s_ls).
// ---------------------------------------------------------------------------
__global__ __launch_bounds__(SWT, 1) void sweep_kernel(
    const float* __restrict__ aggT, const u16* __restrict__ wq,
    const u16* __restrict__ par16, const int* __restrict__ ls,
    const int* __restrict__ nl, float* __restrict__ agg)
{
  extern __shared__ char smem[];
  float* s_agg = (float*)smem;                         // 5*6413*4 = 128,260 B (+4 pad)
  u32*  s_w32  = (u32*)(smem + 128264);                // 12,800 B (6400 u16)
  u32*  s_p32  = (u32*)(smem + 128264 + 12800);        // 12,800 B
  int*  s_ls   = (int*)(smem + 128264 + 25600);        // 2,048 B
  u16*  s_w    = (u16*)s_w32;
  u16*  s_par  = (u16*)s_p32;

  const int bid = blockIdx.x;
  const int b = bid / (NG*13);
  const int r = bid - b*(NG*13);
  const int g = r / 13;
  const int ch0 = (r - g*13) * SCH;
  const int tid = threadIdx.x;
  const int ld = tid & 63;
  const int cw = tid >> 6;          // wave id == owned channel (0..4)
  const int bg = b*NG + g;

  // ---- stage: each wave loads its own channel plane (coalesced float4) ----
  {
    const float4* src = reinterpret_cast<const float4*>(aggT + ((size_t)bg*CHG + ch0 + cw)*NPIX);
    float* dst = s_agg + cw*SPITCH;
    for (int i = ld; i < NPIX/4; i += 64) {
      float4 v = src[i];
      int k = i*4;
      dst[k] = v.x; dst[k+1] = v.y; dst[k+2] = v.z; dst[k+3] = v.w;
    }
  }
  {
    const u32* wsrc = reinterpret_cast<const u32*>(wq + (size_t)bg*NPIX);
    const u32* psrc = reinterpret_cast<const u32*>(par16 + (size_t)b*NPIX);
    for (int i = tid; i < NPIX/2; i += SWT) {
      s_w32[i] = wsrc[i];
      s_p32[i] = psrc[i];
    }
  }
  const int* lsb = ls + b*(NPIX+2);
  const int L = nl[b];
  for (int i = tid; i <= L && i < LSC; i += SWT) s_ls[i] = lsb[i];
  __syncthreads();

  const float qs = 1.0f/65535.0f;
  float* sa = s_agg + cw*SPITCH;      // this wave's private channel plane
  auto LS = [&](int x) -> int { x = min(x, L); return (x < LSC) ? s_ls[x] : lsb[x]; };

  // ---- UP: children (level lev+1) scatter-add into parents. Per-wave.
  //      No hardware wait between levels: in-order DS pipe handles RAW. ----
  {
    int lev = L-2;
    int A = LS(lev), Bv = LS(lev+1), Cv = LS(lev+2);
    while (lev >= 0) {
      int nxt = (lev > 0) ? LS(lev-1) : 0;
      for (int k = Bv + ld; k < Cv; k += 64) {
        int p = s_par[k];
        float wv = (float)s_w[k] * qs;
        atomicAdd(&sa[p], wv * sa[k]);
      }
      asm volatile("" ::: "memory");   // compiler-only: pin level order
      Cv = Bv; Bv = A; A = nxt; --lev;
    }
  }

  // ---- DOWN (in place): out[k] = a + w*(out[p] - w*a). Per-wave. ----
  {
    int lev = 1;
    int A = LS(1), Bv = LS(2);
    while (lev < L) {
      int nxt = LS(lev+2);             // clamped; garbage value never used
      for (int k = A + ld; k < Bv; k += 64) {
        int p = s_par[k];
        float wv = (float)s_w[k] * qs;
        float a  = sa[k];
        float op = sa[p];
        sa[k] = fmaf(wv, op - wv*a, a);
      }
      asm volatile("" ::: "memory");   // compiler-only: pin level order
      A = Bv; Bv = nxt; ++lev;
    }
  }

  __syncthreads();

  // ---- writeback node-major for epilogue (cooperative) ----
  for (int t = tid; t < NPIX*SCH; t += SWT) {
    int k = t / SCH, c = t - k*SCH;
    agg[((size_t)b*NPIX + k)*NODEF + g*CHP + ch0 + c] = s_agg[c*SPITCH + k];
  }
}

// ---------------------------------------------------------------------------
// Epilogue: gather back to spatial, normalize, residual, store
// ---------------------------------------------------------------------------
__global__ __launch_bounds__(256) void epilogue_kernel(
    const float* __restrict__ agg, const int* __restrict__ inv,
    const float* __restrict__ f, const float* __restrict__ gamma,
    float* __restrict__ out)
{
  int idx = blockIdx.x*256 + threadIdx.x;   // b*NPIX + n
  int b = idx / NPIX, n = idx - b*NPIX;
  int k = inv[idx];
  const float* ab = agg + ((size_t)b*NPIX + k)*NODEF;
  float gam = gamma[0];
  const float* fb = f + (size_t)b*CINC*NPIX + n;
  float* ob = out + (size_t)b*CINC*NPIX + n;
  #pragma unroll
  for (int gg = 0; gg < NG; ++gg) {
    float rn = 1.f / (TEPS + ab[gg*CHP + 64]);
    #pragma unroll 4
    for (int cc = 0; cc < 64; ++cc) {
      int ch = gg*64 + cc;
      float res = ab[gg*CHP + cc] * rn;
      float fv  = fb[(size_t)ch*NPIX];
      ob[(size_t)ch*NPIX] = gam*res + fv;
    }
  }
}

// ---------------------------------------------------------------------------
extern "C" void kernel_launch(void* const* d_in, const int* in_sizes, int n_in,
                              void* d_out, int out_size, void* d_ws, size_t ws_size,
                              hipStream_t stream)
{
  const float* f     = (const float*)d_in[0];
  const float* g     = (const float*)d_in[1];
  const float* We    = (const float*)d_in[2];
  const float* Wc    = (const float*)d_in[3];
  const float* Wg    = (const float*)d_in[4];
  const float* beta  = (const float*)d_in[5];
  const float* gamma = (const float*)d_in[6];
  const int* order   = (const int*)d_in[7];
  const int* parent  = (const int*)d_in[8];
  float* out = (float*)d_out;

  char* ws = (char*)d_ws;
  size_t off = 0;
  auto carve = [&](size_t bytes) -> void* {
    void* p = ws + off;
    off = (off + bytes + 255) & ~(size_t)255;
    return p;
  };
  // agg (node-major, 32.8 MB) aliases [emb + xsp] (40.2 MB), both dead
  // by the time sweep_kernel writes it.
  float* agg = (float*)ws;
  float* emb = (float*)carve((size_t)NB*NPIX*NROWS*4);     // 13.5 MB
  float* xsp = (float*)carve((size_t)NB*NPIX*260*4);       // 26.6 MB
  float* aggT= (float*)carve((size_t)NB*NG*CHG*NPIX*4);    // 26.6 MB
  u16*  wq   = (u16*) carve((size_t)NB*NG*NPIX*2);         // 0.2 MB
  u16*  par16= (u16*) carve((size_t)NB*NPIX*2);
  int*  ls   = (int*) carve((size_t)NB*(NPIX+2)*4);
  int*  nl   = (int*) carve((size_t)NB*4);
  int*  inv  = (int*) carve((size_t)NB*NPIX*4);

  const int sweep_lds = 128264 + 12800 + 12800 + 2048;     // 155,912 B
  hipFuncSetAttribute((const void*)sweep_kernel,
                      hipFuncAttributeMaxDynamicSharedMemorySize, sweep_lds);

  hipLaunchKernelGGL(prep_kernel,    dim3(NB),           dim3(PT), 0, stream,
                     order, parent, par16, ls, nl, inv);
  hipLaunchKernelGGL(gemm_kernel,    dim3(NPIX/TP, NB),  dim3(GT), 0, stream,
                     f, g, We, Wc, Wg, emb);
  hipLaunchKernelGGL(wdist_kernel,   dim3(NB*NPIX/256),  dim3(256), 0, stream,
                     emb, order, parent, beta, wq);
  hipLaunchKernelGGL(xbuild_kernel,  dim3(NB*NPIX/256),  dim3(256), 0, stream,
                     f, emb, xsp);
  hipLaunchKernelGGL(gatherT_kernel, dim3(NB*NG*100),    dim3(256), 0, stream,
                     xsp, order, aggT);
  hipLaunchKernelGGL(sweep_kernel,   dim3(NB*NG*13),     dim3(SWT), sweep_lds, stream,
                     aggT, wq, par16, ls, nl, agg);
  hipLaunchKernelGGL(epilogue_kernel,dim3(NB*NPIX/256),  dim3(256), 0, stream,
                     agg, inv, f, gamma, out);
}

// Round 6
// 371.544 us; speedup vs baseline: 1.4573x; 1.1798x over previous
//
#include <hip/hip_runtime.h>
#include <math.h>

// Problem constants (B, CIN, CGD, CE, G, H, W) = (4, 256, 256, 64, 4, 80, 80)
#define NB    4
#define CINC  256
#define NG    4
#define NPIX  6400          // H*W
#define NROWS 132           // 64 embed + 64 guide_embed + 4 conf
#define CHG   65            // tree-filter channels per group (64 + norm)
#define TEPS  1e-8f
#define TP    128           // gemm position tile
#define KC    32            // gemm K chunk
#define GT    256           // gemm threads
#define SCH   5             // sweep channels per block (13 chunks * 5 = 65)
#define SPITCH 6413         // LDS pitch: %32==13 -> clean banks
#define SWT   320           // sweep threads: 5 waves, wave w owns channel w
#define PT    640           // prep threads (6400/640 = 10)
#define LSC   512           // level-start LDS cache entries

typedef unsigned short u16;
typedef unsigned int   u32;

// ---------------------------------------------------------------------------
// Preprocessing: per batch — levels via pointer doubling, level starts,
// u16 parent copy, inverse order. 640 threads = 10 items/thread.
// ---------------------------------------------------------------------------
__global__ __launch_bounds__(PT) void prep_kernel(
    const int* __restrict__ order, const int* __restrict__ parent,
    u16* __restrict__ par16, int* __restrict__ ls,
    int* __restrict__ nl, int* __restrict__ inv)
{
  const int b = blockIdx.x;
  const int tid = threadIdx.x;
  const int* par = parent + b*NPIX;
  const int* ord = order + b*NPIX;
  __shared__ int lvl[NPIX];   // 25.6 KB
  __shared__ int anc[NPIX];   // 25.6 KB
  __shared__ int smax;

  #pragma unroll
  for (int it = 0; it < NPIX/PT; ++it) {
    int k = tid + it*PT;
    int p = par[k];
    lvl[k] = (k == 0) ? 0 : 1;
    anc[k] = p;
    inv[b*NPIX + ord[k]] = k;
    par16[b*NPIX + k] = (u16)p;
  }
  __syncthreads();

  // depth via pointer doubling: 13 rounds (2^13 = 8192 > 6400)
  for (int r = 0; r < 13; ++r) {
    int nlv[NPIX/PT], nan_[NPIX/PT];
    #pragma unroll
    for (int it = 0; it < NPIX/PT; ++it) {
      int k = tid + it*PT;
      int a = anc[k];
      nlv[it]  = lvl[k] + lvl[a];
      nan_[it] = anc[a];
    }
    __syncthreads();
    #pragma unroll
    for (int it = 0; it < NPIX/PT; ++it) {
      int k = tid + it*PT;
      lvl[k] = nlv[it];
      anc[k] = nan_[it];
    }
    __syncthreads();
  }

  if (tid == 0) smax = 0;
  __syncthreads();
  int m = 0;
  #pragma unroll
  for (int it = 0; it < NPIX/PT; ++it) m = max(m, lvl[tid + it*PT]);
  atomicMax(&smax, m);
  __syncthreads();
  if (tid == 0) {
    nl[b] = smax + 1;
    ls[b*(NPIX+2) + smax + 1] = NPIX;
  }
  #pragma unroll
  for (int it = 0; it < NPIX/PT; ++it) {
    int k = tid + it*PT;
    // levels are contiguous position ranges (BFS order)
    if (k == 0 || lvl[k] != lvl[k-1]) ls[b*(NPIX+2) + lvl[k]] = k;
  }
}

// ---------------------------------------------------------------------------
// GEMM: emb_all[b][n][r], r in [0,64)=W_embed@f, [64,128)=W_guide@g,
// [128,132)=sigmoid(W_conf@f). Node-major output for later gathers.
// All inner-loop LDS reads are b128 (weights staged transposed).
// ---------------------------------------------------------------------------
__global__ __launch_bounds__(GT) void gemm_kernel(
    const float* __restrict__ f, const float* __restrict__ g,
    const float* __restrict__ We, const float* __restrict__ Wc,
    const float* __restrict__ Wg, float* __restrict__ emb)
{
  const int b  = blockIdx.y;
  const int t0 = blockIdx.x * TP;
  const int tid = threadIdx.x;
  const int i = tid >> 4;   // 0..15 rowgroup (rows 8i..8i+7)
  const int j = tid & 15;   // 0..15 posgroup

  __shared__ float fT[KC][TP];      // 16 KB
  __shared__ float gT[KC][TP];      // 16 KB
  __shared__ float wTt[KC][136];    // 17.4 KB (transposed, padded pitch)

  float acc[8][8];
  #pragma unroll
  for (int r = 0; r < 8; ++r)
    #pragma unroll
    for (int p = 0; p < 8; ++p) acc[r][p] = 0.f;
  float accc[8];
  #pragma unroll
  for (int p = 0; p < 8; ++p) accc[p] = 0.f;

  const float* fb = f + (size_t)b*CINC*NPIX;
  const float* gb = g + (size_t)b*CINC*NPIX;
  const float (*xT)[TP] = (i < 8) ? fT : gT;   // rows 0..63 use f, 64..127 use g

  for (int kc = 0; kc < CINC; kc += KC) {
    { // stage x tiles: 32x128 each; 16 contiguous floats per thread
      int kk = tid >> 3;
      int p  = (tid & 7) * 16;
      const float4* srcf = reinterpret_cast<const float4*>(fb + (size_t)(kc+kk)*NPIX + t0 + p);
      const float4* srcg = reinterpret_cast<const float4*>(gb + (size_t)(kc+kk)*NPIX + t0 + p);
      float4* df = reinterpret_cast<float4*>(&fT[kk][p]);
      float4* dg = reinterpret_cast<float4*>(&gT[kk][p]);
      #pragma unroll
      for (int q = 0; q < 4; ++q) { df[q] = srcf[q]; dg[q] = srcg[q]; }
    }
    // stage weights transposed: wTt[kb][r]
    for (int s = tid; s < 528; s += GT) {
      int r = s >> 2, kb0 = (s & 3) * 8;
      const float* wsrc;
      if (r < 64)       wsrc = We + r*CINC + kc + kb0;
      else if (r < 128) wsrc = Wg + (r-64)*CINC + kc + kb0;
      else              wsrc = Wc + (r-128)*CINC + kc + kb0;
      const float4* wv = reinterpret_cast<const float4*>(wsrc);
      float4 v0 = wv[0], v1 = wv[1];
      wTt[kb0+0][r]=v0.x; wTt[kb0+1][r]=v0.y; wTt[kb0+2][r]=v0.z; wTt[kb0+3][r]=v0.w;
      wTt[kb0+4][r]=v1.x; wTt[kb0+5][r]=v1.y; wTt[kb0+6][r]=v1.z; wTt[kb0+7][r]=v1.w;
    }
    __syncthreads();

    for (int kk = 0; kk < KC; ++kk) {
      float4 x0 = *reinterpret_cast<const float4*>(&xT[kk][4*j]);
      float4 x1 = *reinterpret_cast<const float4*>(&xT[kk][64 + 4*j]);
      float4 w0 = *reinterpret_cast<const float4*>(&wTt[kk][8*i]);
      float4 w1 = *reinterpret_cast<const float4*>(&wTt[kk][8*i + 4]);
#define FMA8(r, wv) \
      acc[r][0] += (wv)*x0.x; acc[r][1] += (wv)*x0.y; acc[r][2] += (wv)*x0.z; acc[r][3] += (wv)*x0.w; \
      acc[r][4] += (wv)*x1.x; acc[r][5] += (wv)*x1.y; acc[r][6] += (wv)*x1.z; acc[r][7] += (wv)*x1.w;
      FMA8(0, w0.x) FMA8(1, w0.y) FMA8(2, w0.z) FMA8(3, w0.w)
      FMA8(4, w1.x) FMA8(5, w1.y) FMA8(6, w1.z) FMA8(7, w1.w)
#undef FMA8
      if (i < 4) {
        float wcf = wTt[kk][128 + i];
        accc[0] += wcf*x0.x; accc[1] += wcf*x0.y; accc[2] += wcf*x0.z; accc[3] += wcf*x0.w;
        accc[4] += wcf*x1.x; accc[5] += wcf*x1.y; accc[6] += wcf*x1.z; accc[7] += wcf*x1.w;
      }
    }
    __syncthreads();
  }

  float* eb = emb + (size_t)b*NPIX*NROWS;
  #pragma unroll
  for (int p = 0; p < 8; ++p) {
    int n = t0 + ((p >> 2) * 64) + 4*j + (p & 3);
    float4 v0 = make_float4(acc[0][p], acc[1][p], acc[2][p], acc[3][p]);
    float4 v1 = make_float4(acc[4][p], acc[5][p], acc[6][p], acc[7][p]);
    float* base = eb + (size_t)n*NROWS + 8*i;
    *reinterpret_cast<float4*>(base)     = v0;
    *reinterpret_cast<float4*>(base + 4) = v1;
    if (i < 4) eb[(size_t)n*NROWS + 128 + i] = 1.f / (1.f + expf(-accc[p]));
  }
}

// ---------------------------------------------------------------------------
// Edge weights, quantized u16, transposed: wq[b][g][k] = round(65535*w)
// ---------------------------------------------------------------------------
__global__ __launch_bounds__(256) void wdist_kernel(
    const float* __restrict__ emb, const int* __restrict__ order,
    const int* __restrict__ parent, const float* __restrict__ beta,
    u16* __restrict__ wq)
{
  int idx = blockIdx.x*256 + threadIdx.x;   // b*NPIX + k
  int b = idx / NPIX;
  int k = idx - b*NPIX;
  int n  = order[idx];
  int kp = parent[idx];
  int np = order[b*NPIX + kp];
  const float4* e0 = reinterpret_cast<const float4*>(emb + ((size_t)b*NPIX + n )*NROWS);
  const float4* e1 = reinterpret_cast<const float4*>(emb + ((size_t)b*NPIX + np)*NROWS);
  float d[NG] = {0.f, 0.f, 0.f, 0.f};
  #pragma unroll
  for (int q = 0; q < 32; ++q) {            // channels 0..127 (embed then guide_embed)
    float4 a = e0[q], c = e1[q];
    int gg = (q & 15) >> 2;                 // group = (channel%64)/16
    float t0 = a.x-c.x, t1 = a.y-c.y, t2 = a.z-c.z, t3 = a.w-c.w;
    d[gg] += t0*t0 + t1*t1 + t2*t2 + t3*t3;
  }
  #pragma unroll
  for (int gg = 0; gg < NG; ++gg) {
    float bg = beta[gg];
    float w = expf(-(d[gg] + bg*bg));
    wq[((size_t)(b*NG+gg))*NPIX + k] = (u16)(w*65535.f + 0.5f);
  }
}

// ---------------------------------------------------------------------------
// Fused xbuild+gatherT (xsp eliminated): build channel-major ordered tensor
//   aggT[bg][c][k] = f[b][g*64+c][ord[k]] * conf_g[ord[k]]   (c < 64)
//   aggT[bg][64][k] = conf_g[ord[k]]
// Writes coalesced; f-row gathers L2-absorbed. bid = tile*16 + pair keeps a
// given (b,g)'s 50 tiles on one XCD (pair%8 fixed) for L2 row reuse.
// ---------------------------------------------------------------------------
__global__ __launch_bounds__(256) void gatherX_kernel(
    const float* __restrict__ f, const float* __restrict__ emb,
    const int* __restrict__ order, float* __restrict__ aggT)
{
  const int bid = blockIdx.x;          // tile*16 + pair
  const int pair = bid & 15, tile = bid >> 4;
  const int b = pair >> 2, g = pair & 3;
  const int k0 = tile * 128;
  const int tid = threadIdx.x;

  __shared__ int   s_ord[128];
  __shared__ float s_cf[128];
  if (tid < 128) {
    int n = order[b*NPIX + k0 + tid];
    s_ord[tid] = n;
    s_cf[tid]  = emb[((size_t)b*NPIX + n)*NROWS + 128 + g];
  }
  __syncthreads();

  const float* fb = f + (size_t)b*CINC*NPIX + (size_t)g*64*NPIX;
  float* dst = aggT + (size_t)(b*NG+g)*CHG*NPIX + k0;
  const int c0 = tid >> 7;             // 0..1
  const int j  = tid & 127;
  const int n  = s_ord[j];
  const float cf = s_cf[j];
  #pragma unroll 4
  for (int cc = c0; cc < 64; cc += 2) {
    dst[(size_t)cc*NPIX + j] = fb[(size_t)cc*NPIX + n] * cf;
  }
  if (tid < 128) dst[(size_t)64*NPIX + j] = cf;
}

// ---------------------------------------------------------------------------
// Tree filter, LDS-resident. Block = (b, g, 5-channel chunk), 320 threads =
// 5 waves; wave w owns channel w exclusively. DS instructions from one wave
// execute IN ORDER through the LDS pipe, so level->level RAW needs only a
// compiler fence (no hardware waits). R6: writeback goes IN PLACE into aggT
// (coalesced float4, SoA) — kills the 2.4x-amplified node-major scatter.
// ---------------------------------------------------------------------------
__global__ __launch_bounds__(SWT, 1) void sweep_kernel(
    float* __restrict__ aggT, const u16* __restrict__ wq,
    const u16* __restrict__ par16, const int* __restrict__ ls,
    const int* __restrict__ nl)
{
  extern __shared__ char smem[];
  float* s_agg = (float*)smem;                         // 5*6413*4 = 128,260 B (+4 pad)
  u32*  s_w32  = (u32*)(smem + 128264);                // 12,800 B (6400 u16)
  u32*  s_p32  = (u32*)(smem + 128264 + 12800);        // 12,800 B
  int*  s_ls   = (int*)(smem + 128264 + 25600);        // 2,048 B
  u16*  s_w    = (u16*)s_w32;
  u16*  s_par  = (u16*)s_p32;

  const int bid = blockIdx.x;
  const int b = bid / (NG*13);
  const int r = bid - b*(NG*13);
  const int g = r / 13;
  const int ch0 = (r - g*13) * SCH;
  const int tid = threadIdx.x;
  const int ld = tid & 63;
  const int cw = tid >> 6;          // wave id == owned channel (0..4)
  const int bg = b*NG + g;

  // ---- stage: each wave loads its own channel plane (coalesced float4) ----
  {
    const float4* src = reinterpret_cast<const float4*>(aggT + ((size_t)bg*CHG + ch0 + cw)*NPIX);
    float* dst = s_agg + cw*SPITCH;
    for (int i = ld; i < NPIX/4; i += 64) {
      float4 v = src[i];
      int k = i*4;
      dst[k] = v.x; dst[k+1] = v.y; dst[k+2] = v.z; dst[k+3] = v.w;
    }
  }
  {
    const u32* wsrc = reinterpret_cast<const u32*>(wq + (size_t)bg*NPIX);
    const u32* psrc = reinterpret_cast<const u32*>(par16 + (size_t)b*NPIX);
    for (int i = tid; i < NPIX/2; i += SWT) {
      s_w32[i] = wsrc[i];
      s_p32[i] = psrc[i];
    }
  }
  const int* lsb = ls + b*(NPIX+2);
  const int L = nl[b];
  for (int i = tid; i <= L && i < LSC; i += SWT) s_ls[i] = lsb[i];
  __syncthreads();

  const float qs = 1.0f/65535.0f;
  float* sa = s_agg + cw*SPITCH;      // this wave's private channel plane
  auto LS = [&](int x) -> int { x = min(x, L); return (x < LSC) ? s_ls[x] : lsb[x]; };

  // ---- UP: children (level lev+1) scatter-add into parents. Per-wave. ----
  {
    int lev = L-2;
    int A = LS(lev), Bv = LS(lev+1), Cv = LS(lev+2);
    while (lev >= 0) {
      int nxt = (lev > 0) ? LS(lev-1) : 0;
      for (int k = Bv + ld; k < Cv; k += 64) {
        int p = s_par[k];
        float wv = (float)s_w[k] * qs;
        atomicAdd(&sa[p], wv * sa[k]);
      }
      asm volatile("" ::: "memory");   // compiler-only: pin level order
      Cv = Bv; Bv = A; A = nxt; --lev;
    }
  }

  // ---- DOWN (in place): out[k] = a + w*(out[p] - w*a). Per-wave. ----
  {
    int lev = 1;
    int A = LS(1), Bv = LS(2);
    while (lev < L) {
      int nxt = LS(lev+2);             // clamped; garbage value never used
      for (int k = A + ld; k < Bv; k += 64) {
        int p = s_par[k];
        float wv = (float)s_w[k] * qs;
        float a  = sa[k];
        float op = sa[p];
        sa[k] = fmaf(wv, op - wv*a, a);
      }
      asm volatile("" ::: "memory");   // compiler-only: pin level order
      A = Bv; Bv = nxt; ++lev;
    }
  }

  __syncthreads();

  // ---- writeback IN PLACE to aggT (coalesced float4, per-wave channel) ----
  {
    float4* dst = reinterpret_cast<float4*>(aggT + ((size_t)bg*CHG + ch0 + cw)*NPIX);
    const float* srcp = s_agg + cw*SPITCH;
    for (int i = ld; i < NPIX/4; i += 64) {
      int k = i*4;
      dst[i] = make_float4(srcp[k], srcp[k+1], srcp[k+2], srcp[k+3]);
    }
  }
}

// ---------------------------------------------------------------------------
// Epilogue (n-major): out[ch][n] = gamma*filt[ch][inv[n]]/(eps+norm) + f[ch][n]
// f/out coalesced; aggT SoA rows gathered (25.6 KB each, L2-absorbed).
// bid = tile*NB + b keeps each batch's tiles on 2 XCDs.
// ---------------------------------------------------------------------------
__global__ __launch_bounds__(256) void epilogue_kernel(
    const float* __restrict__ aggT, const int* __restrict__ inv,
    const float* __restrict__ f, const float* __restrict__ gamma,
    float* __restrict__ out)
{
  const int bid = blockIdx.x;          // tile*NB + b
  const int b = bid & 3, tile = bid >> 2;
  const int n0 = tile * 64;
  const int tid = threadIdx.x;
  const int g = tid >> 6, j = tid & 63;

  __shared__ int s_k[64];
  if (tid < 64) s_k[tid] = inv[b*NPIX + n0 + tid];
  __syncthreads();

  const int k = s_k[j];
  const float* at = aggT + (size_t)(b*NG + g)*CHG*NPIX;
  const float rn = 1.f / (TEPS + at[(size_t)64*NPIX + k]);
  const float gam = gamma[0];
  const float* fb = f   + (size_t)b*CINC*NPIX + (size_t)g*64*NPIX;
  float*       ob = out + (size_t)b*CINC*NPIX + (size_t)g*64*NPIX;
  #pragma unroll 4
  for (int cc = 0; cc < 64; ++cc) {
    float val = at[(size_t)cc*NPIX + k];
    float fv  = fb[(size_t)cc*NPIX + n0 + j];
    ob[(size_t)cc*NPIX + n0 + j] = fmaf(gam, val*rn, fv);
  }
}

// ---------------------------------------------------------------------------
extern "C" void kernel_launch(void* const* d_in, const int* in_sizes, int n_in,
                              void* d_out, int out_size, void* d_ws, size_t ws_size,
                              hipStream_t stream)
{
  const float* f     = (const float*)d_in[0];
  const float* g     = (const float*)d_in[1];
  const float* We    = (const float*)d_in[2];
  const float* Wc    = (const float*)d_in[3];
  const float* Wg    = (const float*)d_in[4];
  const float* beta  = (const float*)d_in[5];
  const float* gamma = (const float*)d_in[6];
  const int* order   = (const int*)d_in[7];
  const int* parent  = (const int*)d_in[8];
  float* out = (float*)d_out;

  char* ws = (char*)d_ws;
  size_t off = 0;
  auto carve = [&](size_t bytes) -> void* {
    void* p = ws + off;
    off = (off + bytes + 255) & ~(size_t)255;
    return p;
  };
  float* emb = (float*)carve((size_t)NB*NPIX*NROWS*4);     // 13.5 MB
  float* aggT= (float*)carve((size_t)NB*NG*CHG*NPIX*4);    // 26.6 MB (in/out of sweep)
  u16*  wq   = (u16*) carve((size_t)NB*NG*NPIX*2);         // 0.2 MB
  u16*  par16= (u16*) carve((size_t)NB*NPIX*2);
  int*  ls   = (int*) carve((size_t)NB*(NPIX+2)*4);
  int*  nl   = (int*) carve((size_t)NB*4);
  int*  inv  = (int*) carve((size_t)NB*NPIX*4);

  const int sweep_lds = 128264 + 12800 + 12800 + 2048;     // 155,912 B
  hipFuncSetAttribute((const void*)sweep_kernel,
                      hipFuncAttributeMaxDynamicSharedMemorySize, sweep_lds);

  hipLaunchKernelGGL(prep_kernel,    dim3(NB),           dim3(PT), 0, stream,
                     order, parent, par16, ls, nl, inv);
  hipLaunchKernelGGL(gemm_kernel,    dim3(NPIX/TP, NB),  dim3(GT), 0, stream,
                     f, g, We, Wc, Wg, emb);
  hipLaunchKernelGGL(wdist_kernel,   dim3(NB*NPIX/256),  dim3(256), 0, stream,
                     emb, order, parent, beta, wq);
  hipLaunchKernelGGL(gatherX_kernel, dim3(16*(NPIX/128)),dim3(256), 0, stream,
                     f, emb, order, aggT);
  hipLaunchKernelGGL(sweep_kernel,   dim3(NB*NG*13),     dim3(SWT), sweep_lds, stream,
                     aggT, wq, par16, ls, nl);
  hipLaunchKernelGGL(epilogue_kernel,dim3((NPIX/64)*NB), dim3(256), 0, stream,
                     aggT, inv, f, gamma, out);
}